// Round 11
// baseline (146.748 us; speedup 1.0000x reference)
//
#include <hip/hip_runtime.h>
#include <hip/hip_bf16.h>
#include <stdint.h>
#include <stddef.h>

#define B_  4
#define S_  2048
#define D_  1024
#define TB_ 128

typedef float v4f  __attribute__((ext_vector_type(4)));
typedef float v16f __attribute__((ext_vector_type(16)));
typedef short s16x4 __attribute__((ext_vector_type(4)));
typedef short s16x8 __attribute__((ext_vector_type(8)));

#define WAITV(n) asm volatile("s_waitcnt vmcnt(" #n ")" ::: "memory")

__device__ __forceinline__ unsigned short f2bf(float f) {
  union { float f; unsigned u; } x; x.f = f;
  unsigned u = x.u;
  unsigned r = (u + 0x7FFFu + ((u >> 16) & 1u)) >> 16;
  return (unsigned short)r;
}

__device__ __forceinline__ void gld16(const void* g, void* l) {
  __builtin_amdgcn_global_load_lds(
      (const __attribute__((address_space(1))) unsigned int*)g,
      (__attribute__((address_space(3))) unsigned int*)l, 16, 0, 0);
}

// raw barrier (no vmcnt(0) drain) + motion fence
__device__ __forceinline__ void barrier_sync() {
  asm volatile("" ::: "memory");
  __builtin_amdgcn_s_barrier();
  asm volatile("" ::: "memory");
  __builtin_amdgcn_sched_barrier(0);
}

// ---------------- prep: gate + cvt(Q) + cvt(K) + V^T, one dispatch --------
__global__ __launch_bounds__(256) void prep_kernel(
    const float* __restrict__ Q, const float* __restrict__ K,
    const float* __restrict__ V, const float* __restrict__ tb,
    const float* __restrict__ W, const float* __restrict__ bias,
    short* __restrict__ Qb, short* __restrict__ Kb,
    short* __restrict__ VT, float* __restrict__ gate) {
  __shared__ float tile[64][65];
  int bid = blockIdx.x;
  int t = threadIdx.x;
  if (bid < 16384) {                       // bulk f32->bf16 convert (Q or K)
    const float* src = bid < 8192 ? Q : K;
    short* dst = bid < 8192 ? Qb : Kb;
    size_t g = (size_t)(bid & 8191) * 256 + t;
    v4f v = *(const v4f*)(src + g * 4);
    s16x4 o;
    o[0] = (short)f2bf(v[0]); o[1] = (short)f2bf(v[1]);
    o[2] = (short)f2bf(v[2]); o[3] = (short)f2bf(v[3]);
    *(s16x4*)(dst + g * 4) = o;
  } else if (bid < 18432) {                // V [b][s][d] -> V^T [b][d][s]
    int v = bid - 16384;
    int b = v >> 9;
    int rem = v & 511;
    int s0 = (rem & 31) * 64, d0 = (rem >> 5) * 64;
    int tc = t & 63, tr4 = t >> 6;
    const float* src = V + ((size_t)b * S_ + s0) * D_ + d0;
    #pragma unroll
    for (int p = 0; p < 16; ++p) {
      int r = p * 4 + tr4;
      tile[r][tc] = src[(size_t)r * D_ + tc];
    }
    __syncthreads();
    short* dst = VT + ((size_t)b * D_ + d0) * S_ + s0;
    #pragma unroll
    for (int p = 0; p < 16; ++p) {
      int r = p * 4 + tr4;
      dst[(size_t)r * S_ + tc] = (short)f2bf(tile[tc][r]);
    }
  } else {                                 // gate: sigmoid(tb @ W + b)
    int b = t >> 6, l = t & 63;
    float s = tb[b * TB_ + l] * W[l] + tb[b * TB_ + 64 + l] * W[64 + l];
    #pragma unroll
    for (int off = 32; off > 0; off >>= 1) s += __shfl_down(s, off, 64);
    if (l == 0) gate[b] = 1.0f / (1.0f + __expf(-(s + bias[0])));
  }
}

// ---------------- occupancy GEMM (32x32x16): C = A . B^T ------------------
// BK=32, 256 threads (4 waves 2x2), tile (MFR*64) x (NFR*64), dbuf LDS
// small enough for 2-4 blocks/CU: cross-block overlap covers barrier
// drains, staging latency and (critically) the f32 C-write epilogue that
// was device-synchronous at 1 block/CU. Swizzle algebra = R9 adapted to
// 4 chunks/row: LDS[row][c] holds global chunk c^(row&3); reader slot
// (ks*2+hi2)^(row&3). vmcnt ledger: ALOADS+BLOADS per thread per tile.
template<int MTILES, int NTILES, int MFR, int NFR, int KT, int BROWS,
         int LDC, bool GATED>
__global__ __launch_bounds__(256, 2) void gemm_occ(
    const short* __restrict__ Ag, const short* __restrict__ Bg,
    const float* __restrict__ gate, float* __restrict__ Cg) {
  extern __shared__ char lds[];
  constexpr int BM = MFR * 64;
  constexpr int BN = NFR * 64;
  constexpr int ALOADS = BM / 64;         // gld16 per thread (A)
  constexpr int BLOADS = BN / 64;
  constexpr int NT = KT / 32;             // K-tiles
  constexpr int PB = MTILES * NTILES;     // tiles per batch
  constexpr int CPX = (4 * PB) / 8;       // wgs per XCD chunk
  constexpr int ABYTES = BM * 64;         // BM rows x 32 bf16
  constexpr int BUFB = ABYTES + BN * 64;

  int wg = blockIdx.x;
  int swz = (wg & 7) * CPX + (wg >> 3);   // bijective (grid % 8 == 0)
  int b = swz / PB;
  int rem = swz % PB;
  int m0 = (rem / NTILES) * BM;
  int n0 = (rem % NTILES) * BN;

  int tid = threadIdx.x;
  int w = tid >> 6, l = tid & 63;
  int wm = w >> 1, wn = w & 1;
  int col31 = l & 31, hi2 = l >> 5;

  const short* Ab = Ag + (size_t)b * S_ * KT + (size_t)m0 * KT;
  const short* Bb = Bg + (size_t)b * BROWS * KT + (size_t)n0 * KT;

  // staging: thread t covers row j*64 + (t>>2), global chunk (t&3)^(row&3)
  int srow = tid >> 2;                    // 0..63 per j-block
  int schunk = ((tid & 3) ^ (srow & 3)) * 8;  // shorts

  v16f acc[MFR][NFR];
  #pragma unroll
  for (int m = 0; m < MFR; ++m)
    #pragma unroll
    for (int n = 0; n < NFR; ++n)
      #pragma unroll
      for (int j = 0; j < 16; ++j) acc[m][n][j] = 0.0f;

  auto stage = [&](int t, int buf) {
    char* La = lds + buf * BUFB;
    char* Lb = La + ABYTES;
    const short* As = Ab + (size_t)t * 32 + schunk;
    const short* Bs = Bb + (size_t)t * 32 + schunk;
    #pragma unroll
    for (int j = 0; j < ALOADS; ++j)
      gld16(As + (size_t)(j * 64 + srow) * KT, La + j * 4096 + tid * 16);
    #pragma unroll
    for (int j = 0; j < BLOADS; ++j)
      gld16(Bs + (size_t)(j * 64 + srow) * KT, Lb + j * 4096 + tid * 16);
  };

  stage(0, 0);
  int cur = 0;
  for (int t = 0; t < NT; ++t) {
    if (t + 1 < NT) {
      stage(t + 1, cur ^ 1);              // prefetch stays in flight
      if constexpr (ALOADS + BLOADS == 6) WAITV(6); else WAITV(4);
    } else {
      WAITV(0);
    }
    barrier_sync();                       // publish tile t
    const char* Abase = lds + cur * BUFB;
    const char* Bbase = Abase + ABYTES;
    #pragma unroll
    for (int ks = 0; ks < 2; ++ks) {
      int slot = ((ks * 2 + hi2) ^ (col31 & 3)) * 16;
      s16x8 af[MFR], bfr[NFR];
      #pragma unroll
      for (int m = 0; m < MFR; ++m)
        af[m] = *(const s16x8*)(Abase +
                 (size_t)(wm * (MFR * 32) + m * 32 + col31) * 64 + slot);
      #pragma unroll
      for (int n = 0; n < NFR; ++n)
        bfr[n] = *(const s16x8*)(Bbase +
                 (size_t)(wn * (NFR * 32) + n * 32 + col31) * 64 + slot);
      __builtin_amdgcn_s_setprio(1);
      #pragma unroll
      for (int m = 0; m < MFR; ++m)
        #pragma unroll
        for (int n = 0; n < NFR; ++n)
          acc[m][n] = __builtin_amdgcn_mfma_f32_32x32x16_bf16(
              af[m], bfr[n], acc[m][n], 0, 0, 0);
      __builtin_amdgcn_s_setprio(0);
    }
    barrier_sync();                       // reads of buf[cur] done
    cur ^= 1;
  }

  float g = 1.0f;
  if constexpr (GATED) g = gate[b] * 0.03125f;   // sigmoid-gate / sqrt(1024)
  float* Cb = Cg + (size_t)b * S_ * LDC +
              (size_t)(m0 + wm * (MFR * 32)) * LDC + n0 + wn * (NFR * 32);
  #pragma unroll
  for (int mf = 0; mf < MFR; ++mf)
    #pragma unroll
    for (int nf = 0; nf < NFR; ++nf) {
      int c = nf * 32 + col31;
      #pragma unroll
      for (int q = 0; q < 4; ++q)
        #pragma unroll
        for (int j = 0; j < 4; ++j) {
          int r = mf * 32 + q * 8 + 4 * hi2 + j;
          Cb[(size_t)r * LDC + c] = acc[mf][nf][q * 4 + j] * g;
        }
    }
}

// ---------------- row softmax: f32 in-place + bf16 copy for PV ------------
__global__ __launch_bounds__(256) void softmax_kernel(
    float* __restrict__ attn, short* __restrict__ attnb) {
  size_t row = blockIdx.x;
  float* p = attn + row * S_;
  int t = threadIdx.x;
  v4f v0 = *(const v4f*)(p + t * 8);
  v4f v1 = *(const v4f*)(p + t * 8 + 4);
  float m = fmaxf(fmaxf(fmaxf(v0[0], v0[1]), fmaxf(v0[2], v0[3])),
                  fmaxf(fmaxf(v1[0], v1[1]), fmaxf(v1[2], v1[3])));
  #pragma unroll
  for (int off = 32; off > 0; off >>= 1) m = fmaxf(m, __shfl_xor(m, off, 64));
  __shared__ float rm[4], rs[4];
  if ((t & 63) == 0) rm[t >> 6] = m;
  __syncthreads();
  m = fmaxf(fmaxf(rm[0], rm[1]), fmaxf(rm[2], rm[3]));
  float e[8]; float sum = 0.0f;
  #pragma unroll
  for (int j = 0; j < 4; ++j) { e[j] = __expf(v0[j] - m); sum += e[j]; }
  #pragma unroll
  for (int j = 0; j < 4; ++j) { e[4 + j] = __expf(v1[j] - m); sum += e[4 + j]; }
  #pragma unroll
  for (int off = 32; off > 0; off >>= 1) sum += __shfl_xor(sum, off, 64);
  if ((t & 63) == 0) rs[t >> 6] = sum;
  __syncthreads();
  sum = rs[0] + rs[1] + rs[2] + rs[3];
  float inv = 1.0f / sum;
  #pragma unroll
  for (int j = 0; j < 4; ++j) v0[j] = e[j] * inv;
  #pragma unroll
  for (int j = 0; j < 4; ++j) v1[j] = e[4 + j] * inv;
  *(v4f*)(p + t * 8) = v0;
  *(v4f*)(p + t * 8 + 4) = v1;
  s16x8 ob;
  ob[0] = (short)f2bf(v0[0]); ob[1] = (short)f2bf(v0[1]);
  ob[2] = (short)f2bf(v0[2]); ob[3] = (short)f2bf(v0[3]);
  ob[4] = (short)f2bf(v1[0]); ob[5] = (short)f2bf(v1[1]);
  ob[6] = (short)f2bf(v1[2]); ob[7] = (short)f2bf(v1[3]);
  *(s16x8*)(attnb + row * S_ + t * 8) = ob;
}

extern "C" void kernel_launch(void* const* d_in, const int* in_sizes, int n_in,
                              void* d_out, int out_size, void* d_ws, size_t ws_size,
                              hipStream_t stream) {
  (void)in_sizes; (void)n_in; (void)out_size; (void)ws_size;
  const float* Q  = (const float*)d_in[0];
  const float* K  = (const float*)d_in[1];
  const float* V  = (const float*)d_in[2];
  const float* tb = (const float*)d_in[3];
  const float* W  = (const float*)d_in[4];
  const float* bias = (const float*)d_in[5];

  float* out  = (float*)d_out;                       // [4,2048,1024]
  float* attn = out + (size_t)B_ * S_ * D_;          // [4,2048,2048]

  char* ws = (char*)d_ws;
  float* gate = (float*)ws;                          // 4 floats
  short* Qb = (short*)(ws + 256);                    // bf16 [4][2048][1024]
  short* Kb = Qb + (size_t)B_ * S_ * D_;             // bf16 [4][2048][1024]
  short* VT = Kb + (size_t)B_ * S_ * D_;             // bf16 [4][1024][2048]
  short* attnb = Qb;                                 // reuse Qb+Kb: bf16 P

  // QK: tile 256x128 (MFR=4,NFR=2), grid 8*16*4=512 (2 blocks/CU), gated.
  auto* qkf = gemm_occ<8, 16, 4, 2, 1024, 2048, 2048, true>;
  // PV: tile 128x128 (MFR=2,NFR=2), grid 16*8*4=512 (3-4 blocks/CU).
  auto* pvf = gemm_occ<16, 8, 2, 2, 2048, 1024, 1024, false>;
  constexpr int QK_LDS = 2 * (256 + 128) * 32 * 2;   // 49152
  constexpr int PV_LDS = 2 * (128 + 128) * 32 * 2;   // 32768
  (void)hipFuncSetAttribute((const void*)qkf,
      hipFuncAttributeMaxDynamicSharedMemorySize, QK_LDS);
  (void)hipFuncSetAttribute((const void*)pvf,
      hipFuncAttributeMaxDynamicSharedMemorySize, PV_LDS);

  prep_kernel<<<18433, 256, 0, stream>>>(Q, K, V, tb, W, bias,
                                         Qb, Kb, VT, gate);
  qkf<<<512, 256, QK_LDS, stream>>>(Qb, Kb, gate, attn);
  softmax_kernel<<<8192, 256, 0, stream>>>(attn, attnb);
  pvf<<<512, 256, PV_LDS, stream>>>(attnb, VT, gate, out);
}

// Round 13
// 139.163 us; speedup vs baseline: 1.0545x; 1.0545x over previous
//
#include <hip/hip_runtime.h>
#include <hip/hip_bf16.h>
#include <stdint.h>
#include <stddef.h>

#define B_  4
#define S_  2048
#define D_  1024
#define TB_ 128

typedef float v4f  __attribute__((ext_vector_type(4)));
typedef short s16x4 __attribute__((ext_vector_type(4)));
typedef short s16x8 __attribute__((ext_vector_type(8)));

#define WAITV(n) asm volatile("s_waitcnt vmcnt(" #n ")" ::: "memory")

__device__ __forceinline__ unsigned short f2bf(float f) {
  union { float f; unsigned u; } x; x.f = f;
  unsigned u = x.u;
  unsigned r = (u + 0x7FFFu + ((u >> 16) & 1u)) >> 16;
  return (unsigned short)r;
}

__device__ __forceinline__ void gld16(const void* g, void* l) {
  __builtin_amdgcn_global_load_lds(
      (const __attribute__((address_space(1))) unsigned int*)g,
      (__attribute__((address_space(3))) unsigned int*)l, 16, 0, 0);
}

// raw barrier (no vmcnt(0) drain) + motion fence
__device__ __forceinline__ void barrier_sync() {
  asm volatile("" ::: "memory");
  __builtin_amdgcn_s_barrier();
  asm volatile("" ::: "memory");
  __builtin_amdgcn_sched_barrier(0);
}

// ---------------- prep: gate + cvt(Q) + cvt(K) + V^T, one dispatch --------
__global__ __launch_bounds__(256) void prep_kernel(
    const float* __restrict__ Q, const float* __restrict__ K,
    const float* __restrict__ V, const float* __restrict__ tb,
    const float* __restrict__ W, const float* __restrict__ bias,
    short* __restrict__ Qb, short* __restrict__ Kb,
    short* __restrict__ VT, float* __restrict__ gate) {
  __shared__ float tile[64][65];
  int bid = blockIdx.x;
  int t = threadIdx.x;
  if (bid < 16384) {                       // bulk f32->bf16 convert (Q or K)
    const float* src = bid < 8192 ? Q : K;
    short* dst = bid < 8192 ? Qb : Kb;
    size_t g = (size_t)(bid & 8191) * 256 + t;
    v4f v = *(const v4f*)(src + g * 4);
    s16x4 o;
    o[0] = (short)f2bf(v[0]); o[1] = (short)f2bf(v[1]);
    o[2] = (short)f2bf(v[2]); o[3] = (short)f2bf(v[3]);
    *(s16x4*)(dst + g * 4) = o;
  } else if (bid < 18432) {                // V [b][s][d] -> V^T [b][d][s]
    int v = bid - 16384;
    int b = v >> 9;
    int rem = v & 511;
    int s0 = (rem & 31) * 64, d0 = (rem >> 5) * 64;
    int tc = t & 63, tr4 = t >> 6;
    const float* src = V + ((size_t)b * S_ + s0) * D_ + d0;
    #pragma unroll
    for (int p = 0; p < 16; ++p) {
      int r = p * 4 + tr4;
      tile[r][tc] = src[(size_t)r * D_ + tc];
    }
    __syncthreads();
    short* dst = VT + ((size_t)b * D_ + d0) * S_ + s0;
    #pragma unroll
    for (int p = 0; p < 16; ++p) {
      int r = p * 4 + tr4;
      dst[(size_t)r * S_ + tc] = (short)f2bf(tile[tc][r]);
    }
  } else {                                 // gate: sigmoid(tb @ W + b)
    int b = t >> 6, l = t & 63;
    float s = tb[b * TB_ + l] * W[l] + tb[b * TB_ + 64 + l] * W[64 + l];
    #pragma unroll
    for (int off = 32; off > 0; off >>= 1) s += __shfl_down(s, off, 64);
    if (l == 0) gate[b] = 1.0f / (1.0f + __expf(-(s + bias[0])));
  }
}

// ---------------- cohort GEMM: C = A(256xK) . B(128xK)^T ------------------
// Tile 256x128, 512 threads = 8 waves (4M x 2N), wave 64x64, 16x16x32
// MFMA with MFR=NFR=4 (0.5 LDS-reads/MFMA — best ratio). BK=64, 2-buffer,
// counted WAITV(6) (6 gld16/thread/tile: A 4 + B 2), XOR slot swizzle
// (rule 21, R5-verified algebra), setprio clusters. QK grid = 512 blocks
// at 1 block/CU -> 2 cohorts: cohort 2's K-loops hide cohort 1's 64MB f32
// epilogue burst (the suspected additive cost at synchronized 1-cohort
// grids). LDS 96KB.
template<int MTILES, int NTILES, int KT, int BROWS, int LDC, bool GATED>
__global__ __launch_bounds__(512, 1) void gemm_coh(
    const short* __restrict__ Ag, const short* __restrict__ Bg,
    const float* __restrict__ gate, float* __restrict__ Cg) {
  extern __shared__ char lds[];
  constexpr int NT = KT / 64;
  constexpr int PB = MTILES * NTILES;     // tiles per batch
  constexpr int CPX = (4 * PB) / 8;       // wgs per XCD chunk
  constexpr int ABYTES = 256 * 128;       // 32 KB
  constexpr int BUFB = ABYTES + 128 * 128;  // + 16 KB B

  int wg = blockIdx.x;
  int swz = (wg & 7) * CPX + (wg >> 3);   // bijective (grid % 8 == 0)
  int b = swz / PB;
  int rem = swz % PB;
  int m0 = (rem / NTILES) * 256;
  int n0 = (rem % NTILES) * 128;

  int tid = threadIdx.x;
  int w = tid >> 6, l = tid & 63;
  int wm = w >> 1, wn = w & 1;
  int l7 = l & 7, fr = l & 15, hi = l >> 4;

  const short* Ab = Ag + (size_t)b * S_ * KT + (size_t)m0 * KT;
  const short* Bb = Bg + (size_t)b * BROWS * KT + (size_t)n0 * KT;

  // staging: linear LDS dest; inverse-swizzled global chunk (rule 21)
  int srow8 = l >> 3;
  int schunk = (l7 ^ srow8) * 8;          // shorts

  v4f acc[4][4];
  #pragma unroll
  for (int m = 0; m < 4; ++m)
    #pragma unroll
    for (int n = 0; n < 4; ++n)
      #pragma unroll
      for (int j = 0; j < 4; ++j) acc[m][n][j] = 0.0f;

  auto stage = [&](int t, int buf) {
    char* La = lds + buf * BUFB;
    char* Lb = La + ABYTES;
    const short* As = Ab + (size_t)t * 64 + schunk;
    const short* Bs = Bb + (size_t)t * 64 + schunk;
    #pragma unroll
    for (int j = 0; j < 4; ++j) {
      int blk = w * 4 + j;                // 32 blocks x 8 rows = 256
      gld16(As + (size_t)(blk * 8 + srow8) * KT, La + blk * 1024);
    }
    #pragma unroll
    for (int j = 0; j < 2; ++j) {
      int blk = w * 2 + j;                // 16 blocks x 8 rows = 128
      gld16(Bs + (size_t)(blk * 8 + srow8) * KT, Lb + blk * 1024);
    }
  };

  stage(0, 0);
  int cur = 0;
  for (int t = 0; t < NT; ++t) {
    if (t + 1 < NT) {
      stage(t + 1, cur ^ 1);              // prefetch stays in flight
      WAITV(6);                           // tile t landed (t+1's 6 pending)
    } else {
      WAITV(0);
    }
    barrier_sync();                       // publish tile t
    const char* Abase = lds + cur * BUFB;
    const char* Bbase = Abase + ABYTES;
    #pragma unroll
    for (int kk = 0; kk < 2; ++kk) {
      int slot = ((kk * 4 + hi) ^ l7) * 16;
      s16x8 af[4], bfr[4];
      #pragma unroll
      for (int m = 0; m < 4; ++m)
        af[m] = *(const s16x8*)(Abase +
                 (size_t)(wm * 64 + m * 16 + fr) * 128 + slot);
      #pragma unroll
      for (int n = 0; n < 4; ++n)
        bfr[n] = *(const s16x8*)(Bbase +
                 (size_t)(wn * 64 + n * 16 + fr) * 128 + slot);
      __builtin_amdgcn_s_setprio(1);
      #pragma unroll
      for (int m = 0; m < 4; ++m)
        #pragma unroll
        for (int n = 0; n < 4; ++n)
          acc[m][n] = __builtin_amdgcn_mfma_f32_16x16x32_bf16(
              af[m], bfr[n], acc[m][n], 0, 0, 0);
      __builtin_amdgcn_s_setprio(0);
    }
    barrier_sync();                       // reads of buf[cur] done
    cur ^= 1;
  }

  float g = 1.0f;
  if constexpr (GATED) g = gate[b] * 0.03125f;   // sigmoid-gate / sqrt(1024)
  float* Cb = Cg + (size_t)b * S_ * LDC +
              (size_t)(m0 + wm * 64) * LDC + n0 + wn * 64;
  #pragma unroll
  for (int mf = 0; mf < 4; ++mf)
    #pragma unroll
    for (int nf = 0; nf < 4; ++nf) {
      int r0 = mf * 16 + hi * 4;
      int c = nf * 16 + fr;
      #pragma unroll
      for (int j = 0; j < 4; ++j)
        Cb[(size_t)(r0 + j) * LDC + c] = acc[mf][nf][j] * g;
    }
}

// ---------------- row softmax: f32 in-place + bf16 copy for PV ------------
__global__ __launch_bounds__(256) void softmax_kernel(
    float* __restrict__ attn, short* __restrict__ attnb) {
  size_t row = blockIdx.x;
  float* p = attn + row * S_;
  int t = threadIdx.x;
  v4f v0 = *(const v4f*)(p + t * 8);
  v4f v1 = *(const v4f*)(p + t * 8 + 4);
  float m = fmaxf(fmaxf(fmaxf(v0[0], v0[1]), fmaxf(v0[2], v0[3])),
                  fmaxf(fmaxf(v1[0], v1[1]), fmaxf(v1[2], v1[3])));
  #pragma unroll
  for (int off = 32; off > 0; off >>= 1) m = fmaxf(m, __shfl_xor(m, off, 64));
  __shared__ float rm[4], rs[4];
  if ((t & 63) == 0) rm[t >> 6] = m;
  __syncthreads();
  m = fmaxf(fmaxf(rm[0], rm[1]), fmaxf(rm[2], rm[3]));
  float e[8]; float sum = 0.0f;
  #pragma unroll
  for (int j = 0; j < 4; ++j) { e[j] = __expf(v0[j] - m); sum += e[j]; }
  #pragma unroll
  for (int j = 0; j < 4; ++j) { e[4 + j] = __expf(v1[j] - m); sum += e[4 + j]; }
  #pragma unroll
  for (int off = 32; off > 0; off >>= 1) sum += __shfl_xor(sum, off, 64);
  if ((t & 63) == 0) rs[t >> 6] = sum;
  __syncthreads();
  sum = rs[0] + rs[1] + rs[2] + rs[3];
  float inv = 1.0f / sum;
  #pragma unroll
  for (int j = 0; j < 4; ++j) v0[j] = e[j] * inv;
  #pragma unroll
  for (int j = 0; j < 4; ++j) v1[j] = e[4 + j] * inv;
  *(v4f*)(p + t * 8) = v0;
  *(v4f*)(p + t * 8 + 4) = v1;
  s16x8 ob;
  ob[0] = (short)f2bf(v0[0]); ob[1] = (short)f2bf(v0[1]);
  ob[2] = (short)f2bf(v0[2]); ob[3] = (short)f2bf(v0[3]);
  ob[4] = (short)f2bf(v1[0]); ob[5] = (short)f2bf(v1[1]);
  ob[6] = (short)f2bf(v1[2]); ob[7] = (short)f2bf(v1[3]);
  *(s16x8*)(attnb + row * S_ + t * 8) = ob;
}

extern "C" void kernel_launch(void* const* d_in, const int* in_sizes, int n_in,
                              void* d_out, int out_size, void* d_ws, size_t ws_size,
                              hipStream_t stream) {
  (void)in_sizes; (void)n_in; (void)out_size; (void)ws_size;
  const float* Q  = (const float*)d_in[0];
  const float* K  = (const float*)d_in[1];
  const float* V  = (const float*)d_in[2];
  const float* tb = (const float*)d_in[3];
  const float* W  = (const float*)d_in[4];
  const float* bias = (const float*)d_in[5];

  float* out  = (float*)d_out;                       // [4,2048,1024]
  float* attn = out + (size_t)B_ * S_ * D_;          // [4,2048,2048]

  char* ws = (char*)d_ws;
  float* gate = (float*)ws;                          // 4 floats
  short* Qb = (short*)(ws + 256);                    // bf16 [4][2048][1024]
  short* Kb = Qb + (size_t)B_ * S_ * D_;             // bf16 [4][2048][1024]
  short* VT = Kb + (size_t)B_ * S_ * D_;             // bf16 [4][1024][2048]
  short* attnb = Qb;                                 // reuse Qb+Kb: bf16 P

  // QK: 8 m-tiles x 16 n-tiles x 4 = 512 blocks (2 cohorts), gated.
  auto* qkf = gemm_coh<8, 16, 1024, 2048, 2048, true>;
  // PV: 8 m-tiles x 8 n-tiles x 4 = 256 blocks.
  auto* pvf = gemm_coh<8, 8, 2048, 1024, 1024, false>;
  constexpr int G_LDS = 2 * (256 + 128) * 64 * 2;    // 98304
  (void)hipFuncSetAttribute((const void*)qkf,
      hipFuncAttributeMaxDynamicSharedMemorySize, G_LDS);
  (void)hipFuncSetAttribute((const void*)pvf,
      hipFuncAttributeMaxDynamicSharedMemorySize, G_LDS);

  prep_kernel<<<18433, 256, 0, stream>>>(Q, K, V, tb, W, bias,
                                         Qb, Kb, VT, gate);
  qkf<<<512, 512, G_LDS, stream>>>(Qb, Kb, gate, attn);
  softmax_kernel<<<8192, 256, 0, stream>>>(attn, attnb);
  pvf<<<256, 512, G_LDS, stream>>>(attnb, VT, gate, out);
}